// Round 8
// baseline (427.994 us; speedup 1.0000x reference)
//
#include <hip/hip_runtime.h>

// Problem constants (B, L, H, D) = (4, 4096, 8, 64), FACTOR=5
#define NB 4
#define LSEQ 4096
#define NH 8
#define ND 64
#define NSAMP 45
#define NTOP 45
#define ACH 256            // keys per attention chunk
#define NCH (LSEQ / ACH)   // 16 chunks
#define SENT 0x7fffffff

typedef float f32x4 __attribute__((ext_vector_type(4)));

// ---------------------------------------------------------------------------
// Kernel 0 (prep): per l, bucket-sort the 45 (idx,s) pairs by 256-row chunk,
// then split by sorted-position PARITY into two contiguous 24-int streams
// (A = even positions, 23 used; B = odd, 22 used; sentinel-terminated).
// Each compute_M parity-thread walks its own stride-1 stream.
// ---------------------------------------------------------------------------
__global__ __launch_bounds__(256) void prep_kernel(
        const int* __restrict__ idxS, int* __restrict__ sortedAB) {
    int t = threadIdx.x;
    int l = blockIdx.x * 256 + t;
    const int* is = idxS + (size_t)l * NSAMP;
    __shared__ int cnt[256][17];
    #pragma unroll
    for (int c = 0; c < 16; ++c) cnt[t][c] = 0;
    for (int s = 0; s < NSAMP; ++s) cnt[t][is[s] >> 8] += 1;
    int run = 0;
    #pragma unroll
    for (int c = 0; c < 16; ++c) { int v = cnt[t][c]; cnt[t][c] = run; run += v; }
    int* ab = sortedAB + (size_t)l * 48;
    ab[23] = SENT; ab[46] = SENT; ab[47] = SENT;   // unused tail slots
    for (int s = 0; s < NSAMP; ++s) {
        int idx = is[s];
        int p = cnt[t][idx >> 8]++;                 // sorted position 0..44
        ab[(p & 1) * 24 + (p >> 1)] = (idx << 8) | s;
    }
}

// ---------------------------------------------------------------------------
// Kernel 1: M[b,h,l] = max_s(q.k_s) - sum_s(q.k_s)/LSEQ.
// Round-13: Plds removed (was 92 KB -> capped LDS at 1 block/CU). Fold is
// now running (max, sum) in chunk-sorted order: max is bit-exact under any
// order; sum is deterministic (sorted, parity-merged) and perturbs M by
// ~1 ulp << the ~0.05 top-45 boundary gap -> selection stable.
// Two PARITY THREADS per l (t<256: even sorted positions, t>=256: odd) keep
// all 16 waves busy in every chunk; 4 KB LDS reduction merges the halves.
// LDS = Ks 69632 + red 4096 = 73728 -> 2 blocks/CU -> 4 waves/SIMD
// (was 2). Grid 512 x 512. Dot tree byte-identical. XCD pinning kept.
// ---------------------------------------------------------------------------
__global__ __launch_bounds__(512, 4) void compute_M_kernel(
        const float* __restrict__ Q,
        const float* __restrict__ K,
        const int* __restrict__ sortedAB,
        float* __restrict__ Mout) {
    int xcd = blockIdx.x & 7;
    int sub = blockIdx.x >> 3;             // 0..63
    int bh  = (xcd << 2) | (sub & 3);      // 4 bh per XCD -> 4MB L2 K stream
    int lt  = sub >> 2;                    // 0..15 (256-l tile)
    int b = bh >> 3, h = bh & 7;
    int t = threadIdx.x;                   // 0..511
    int lloc = t & 255;
    int par  = t >> 8;                     // 0: even positions, 1: odd
    int l = (lt << 8) | lloc;

    __shared__ float Ks[256 * 68];
    __shared__ float redM[512];
    __shared__ float redS[512];

    // Q row in regs (nontemporal: one-shot stream, keep L2 for K).
    f32x4 qa[16];
    {
        const f32x4* qp0 = reinterpret_cast<const f32x4*>(
            Q + (((size_t)b * LSEQ + l) * NH + h) * ND);
        #pragma unroll
        for (int i = 0; i < 16; ++i) qa[i] = __builtin_nontemporal_load(qp0 + i);
    }

    // EXACT original tree: products, off=32 fused, then 16/8/4/2/1.
    auto dotQK = [&](const f32x4 (&q4)[16], const float* kr) -> float {
        const f32x4* k4 = reinterpret_cast<const f32x4*>(kr);
        float w[32];
        #pragma unroll
        for (int i = 0; i < 8; ++i) {
            f32x4 a = q4[i], bb = k4[i], c = q4[i + 8], d4 = k4[i + 8];
            w[4 * i + 0] = __fadd_rn(__fmul_rn(a.x, bb.x), __fmul_rn(c.x, d4.x));
            w[4 * i + 1] = __fadd_rn(__fmul_rn(a.y, bb.y), __fmul_rn(c.y, d4.y));
            w[4 * i + 2] = __fadd_rn(__fmul_rn(a.z, bb.z), __fmul_rn(c.z, d4.z));
            w[4 * i + 3] = __fadd_rn(__fmul_rn(a.w, bb.w), __fmul_rn(c.w, d4.w));
        }
        #pragma unroll
        for (int off = 16; off; off >>= 1) {
            #pragma unroll
            for (int i = 0; i < off; ++i) w[i] = __fadd_rn(w[i], w[i + off]);
        }
        return w[0];
    };

    const int* sp = sortedAB + (size_t)l * 48 + par * 24;
    int ptr = 0;
    int pk = sp[0];

    size_t kbh = ((size_t)b * LSEQ * NH + h) * ND;

    float maxv = -INFINITY;
    float sumv = 0.0f;

    for (int c = 0; c < 16; ++c) {
        // stage rows [c*256, c*256+256): 4096 f32x4 over 512 threads = 8 ea.
        #pragma unroll
        for (int i = 0; i < 8; ++i) {
            int flat = i * 512 + t;
            int row = flat >> 4, col = flat & 15;
            f32x4 v = *reinterpret_cast<const f32x4*>(
                K + kbh + (size_t)(c * 256 + row) * (NH * ND) + col * 4);
            *reinterpret_cast<f32x4*>(&Ks[row * 68 + col * 4]) = v;
        }
        __syncthreads();

        while ((pk >> 16) == c) {
            int r = (pk >> 8) & 255;
            float p = dotQK(qa, &Ks[r * 68]);
            maxv = fmaxf(maxv, p);
            sumv = __fadd_rn(sumv, p);
            ++ptr;
            pk = sp[ptr];
        }
        __syncthreads();
    }

    // merge parity halves: max exact; sum in fixed (A,B) order.
    redM[t] = maxv; redS[t] = sumv;
    __syncthreads();
    if (t < 256) {
        float m = fmaxf(redM[t], redM[t + 256]);
        float s = __fadd_rn(redS[t], redS[t + 256]);
        Mout[(size_t)bh * LSEQ + l] = m - s * (1.0f / (float)LSEQ);
    }
}

// ---------------------------------------------------------------------------
// Kernel 2: top-45 per (b,h). UNCHANGED (selection semantics frozen).
// ---------------------------------------------------------------------------
__global__ __launch_bounds__(256) void topk_kernel(
        const float* __restrict__ M, int* __restrict__ Mtop) {
    int bh = blockIdx.x;
    int t = threadIdx.x;
    int wave = t >> 6, lane = t & 63;
    const float* m = M + (size_t)bh * LSEQ;

    float rv[16];
    #pragma unroll
    for (int k = 0; k < 16; ++k) rv[k] = m[t + (k << 8)];

    __shared__ float wv[4];
    __shared__ int   wi[4];
    __shared__ int   winIdx;

    for (int iter = 0; iter < NTOP; ++iter) {
        float bv = -INFINITY; int bi = 0x7fffffff;
        #pragma unroll
        for (int k = 0; k < 16; ++k) {
            float v = rv[k];
            if (v > bv) { bv = v; bi = t + (k << 8); }
        }
        #pragma unroll
        for (int off = 1; off < 64; off <<= 1) {
            float ov = __shfl_xor(bv, off, 64);
            int   oi = __shfl_xor(bi, off, 64);
            if (ov > bv || (ov == bv && oi < bi)) { bv = ov; bi = oi; }
        }
        if (lane == 0) { wv[wave] = bv; wi[wave] = bi; }
        __syncthreads();
        if (t == 0) {
            float cv = wv[0]; int ci = wi[0];
            for (int ww = 1; ww < 4; ++ww) {
                if (wv[ww] > cv || (wv[ww] == cv && wi[ww] < ci)) { cv = wv[ww]; ci = wi[ww]; }
            }
            winIdx = ci;
            Mtop[bh * NTOP + iter] = ci;
        }
        __syncthreads();
        int widx = winIdx;
        #pragma unroll
        for (int k = 0; k < 16; ++k)
            if (widx == t + (k << 8)) rv[k] = -INFINITY;
        __syncthreads();
    }
}

// ---------------------------------------------------------------------------
// Kernel 3a/3b: V cumsum. UNCHANGED.
// ---------------------------------------------------------------------------
__global__ __launch_bounds__(256) void cumsumA_kernel(
        const float* __restrict__ V, float* __restrict__ chunkSums) {
    int blk = blockIdx.x;
    int c = blk & 15;
    int bh = blk >> 4;
    int h = bh & (NH - 1);
    int b = bh >> 3;
    int g = threadIdx.x >> 6, d = threadIdx.x & 63;

    const size_t rstride = (size_t)NH * ND;
    size_t vbase = (size_t)b * LSEQ * rstride + (size_t)h * ND + d;

    int l0 = c * 256 + g * 64;
    float s = 0.0f;
    for (int l = l0; l < l0 + 64; ++l) s += V[vbase + (size_t)l * rstride];

    __shared__ float part[4][ND];
    part[g][d] = s;
    __syncthreads();
    if (threadIdx.x < ND)
        chunkSums[(size_t)blk * ND + d] =
            part[0][d] + part[1][d] + part[2][d] + part[3][d];
}

__global__ __launch_bounds__(256) void cumsumC_kernel(
        const float* __restrict__ V, const float* __restrict__ chunkSums,
        float* __restrict__ out) {
    int blk = blockIdx.x;
    int c = blk & 15;
    int bh = blk >> 4;
    int h = bh & (NH - 1);
    int b = bh >> 3;
    int g = threadIdx.x >> 6, d = threadIdx.x & 63;

    const size_t rstride = (size_t)NH * ND;
    size_t vbase = (size_t)b * LSEQ * rstride + (size_t)h * ND + d;

    float run = 0.0f;
    for (int cc = 0; cc < c; ++cc)
        run += chunkSums[((size_t)bh * 16 + cc) * ND + d];

    int l0 = c * 256 + g * 64;
    float s = 0.0f;
    for (int l = l0; l < l0 + 64; ++l) s += V[vbase + (size_t)l * rstride];
    __shared__ float part[4][ND];
    part[g][d] = s;
    __syncthreads();
    for (int gg = 0; gg < g; ++gg) run += part[gg][d];

    size_t obase = (size_t)bh * LSEQ * ND + d;
    for (int l = l0; l < l0 + 64; ++l) {
        run += V[vbase + (size_t)l * rstride];
        out[obase + (size_t)l * ND] = run;
    }
}

// ---------------------------------------------------------------------------
// Kernel 4: flash split-K attention (r11). UNCHANGED.
// ---------------------------------------------------------------------------
__global__ __launch_bounds__(256, 1) void attn_partial_kernel(
        const float* __restrict__ Q, const float* __restrict__ K,
        const float* __restrict__ V, const int* __restrict__ Mtop,
        float* __restrict__ part) {
    int bh = blockIdx.x >> 4;
    int c  = blockIdx.x & 15;
    int b = bh >> 3, h = bh & 7;
    int t = threadIdx.x;
    int w = t >> 6, lane = t & 63;
    int jj = lane >> 4, dq = lane & 15;

    __shared__ float Qs[NTOP * ND];
    __shared__ int   posS[NTOP];
    __shared__ float Vs[64][68];
    __shared__ float Pw[4][64];

    size_t base = ((size_t)b * LSEQ * NH + h) * ND;

    if (t < NTOP) posS[t] = Mtop[bh * NTOP + t];
    __syncthreads();
    for (int idx = t; idx < NTOP * 16; idx += 256) {
        int u = idx >> 4, cg = idx & 15;
        f32x4 v = *reinterpret_cast<const f32x4*>(
            Q + base + (size_t)posS[u] * (NH * ND) + cg * 4);
        *reinterpret_cast<f32x4*>(&Qs[u * ND + cg * 4]) = v;
    }

    f32x4 o[12];
    float mreg[12], sreg[12];
    #pragma unroll
    for (int qi = 0; qi < 12; ++qi) {
        o[qi] = 0.0f; mreg[qi] = -INFINITY; sreg[qi] = 0.0f;
    }

    for (int tt = 0; tt < ACH / 64; ++tt) {
        int tile0 = c * ACH + tt * 64;
        __syncthreads();
        #pragma unroll
        for (int i = 0; i < 4; ++i) {
            int flat = i * 256 + t;
            int r = flat >> 4, cg = flat & 15;
            f32x4 v = *reinterpret_cast<const f32x4*>(
                V + base + (size_t)(tile0 + r) * (NH * ND) + cg * 4);
            *reinterpret_cast<f32x4*>(&Vs[r][cg * 4]) = v;
        }
        __syncthreads();

        f32x4 kreg[16];
        #pragma unroll
        for (int i = 0; i < 16; ++i)
            kreg[i] = *reinterpret_cast<const f32x4*>(
                K + base + (size_t)(tile0 + lane) * (NH * ND) + i * 4);

        #pragma unroll
        for (int qi = 0; qi < 12; ++qi) {
            int u = w + 4 * qi;
            if (u >= NTOP) continue;
            int pu = posS[u];
            if (pu < tile0) continue;

            float a0 = 0, a1 = 0, a2 = 0, a3 = 0;
            #pragma unroll
            for (int di = 0; di < 16; ++di) {
                f32x4 qv = *reinterpret_cast<const f32x4*>(&Qs[u * ND + di * 4]);
                a0 = fmaf(qv.x, kreg[di].x, a0);
                a1 = fmaf(qv.y, kreg[di].y, a1);
                a2 = fmaf(qv.z, kreg[di].z, a2);
                a3 = fmaf(qv.w, kreg[di].w, a3);
            }
            float sc = ((a0 + a1) + (a2 + a3)) * 0.125f;
            if (tile0 + lane > pu) sc = -INFINITY;

            float tmax = sc;
            #pragma unroll
            for (int off = 1; off < 64; off <<= 1)
                tmax = fmaxf(tmax, __shfl_xor(tmax, off, 64));
            float mold = mreg[qi];
            float mnew = fmaxf(mold, tmax);
            float alpha = __expf(mold - mnew);
            float e = __expf(sc - mnew);
            float esum = e;
            #pragma unroll
            for (int off = 1; off < 64; off <<= 1)
                esum += __shfl_xor(esum, off, 64);
            sreg[qi] = sreg[qi] * alpha + esum;
            mreg[qi] = mnew;
            Pw[w][lane] = e;
            o[qi] *= alpha;
            #pragma unroll
            for (int i = 0; i < 16; ++i) {
                float pe = Pw[w][i * 4 + jj];
                f32x4 vv = *reinterpret_cast<const f32x4*>(&Vs[i * 4 + jj][dq * 4]);
                o[qi] += vv * pe;
            }
        }
    }

    #pragma unroll
    for (int qi = 0; qi < 12; ++qi) {
        int u = w + 4 * qi;
        if (u >= NTOP) continue;
        if (posS[u] < c * ACH) continue;
        f32x4 oo = o[qi];
        #pragma unroll
        for (int off = 16; off <= 32; off <<= 1) {
            oo.x += __shfl_xor(oo.x, off, 64);
            oo.y += __shfl_xor(oo.y, off, 64);
            oo.z += __shfl_xor(oo.z, off, 64);
            oo.w += __shfl_xor(oo.w, off, 64);
        }
        size_t pb = ((size_t)(bh * NTOP + u) * NCH + c) * 72;
        if (lane < 16)
            *reinterpret_cast<f32x4*>(&part[pb + 4 + dq * 4]) = oo;
        if (lane == 0) { part[pb] = mreg[qi]; part[pb + 1] = sreg[qi]; }
    }
}

// ---------------------------------------------------------------------------
// Kernel 5: merge chunk partials -> compact ctx. UNCHANGED.
// ---------------------------------------------------------------------------
__global__ __launch_bounds__(256) void attn_merge_kernel(
        const float* __restrict__ part, const int* __restrict__ Mtop,
        float* __restrict__ ctx) {
    int j = blockIdx.x * 4 + (threadIdx.x >> 6);
    int lane = threadIdx.x & 63;
    int bh = j / NTOP, u = j - bh * NTOP;
    int pos = Mtop[bh * NTOP + u];
    int cmax = pos >> 8;
    size_t pb0 = (size_t)(bh * NTOP + u) * NCH * 72;
    float m = -INFINITY;
    for (int cc = 0; cc <= cmax; ++cc)
        m = fmaxf(m, part[pb0 + (size_t)cc * 72]);
    float S = 0.0f, oacc = 0.0f;
    for (int cc = 0; cc <= cmax; ++cc) {
        float mc = part[pb0 + (size_t)cc * 72];
        float sc = part[pb0 + (size_t)cc * 72 + 1];
        float wgt = __expf(mc - m);
        S = fmaf(sc, wgt, S);
        oacc = fmaf(part[pb0 + (size_t)cc * 72 + 4 + lane], wgt, oacc);
    }
    ctx[(size_t)j * ND + lane] = oacc / S;
}

// ---------------------------------------------------------------------------
// Kernel 6: scatter ctx rows into out AFTER cumsum. UNCHANGED.
// ---------------------------------------------------------------------------
__global__ __launch_bounds__(256) void scatter_kernel(
        const float* __restrict__ ctx, const int* __restrict__ Mtop,
        float* __restrict__ out) {
    int j = blockIdx.x * 4 + (threadIdx.x >> 6);
    int lane = threadIdx.x & 63;
    int bh = j / NTOP, u = j - bh * NTOP;
    int pos = Mtop[bh * NTOP + u];
    out[((size_t)bh * LSEQ + pos) * ND + lane] = ctx[(size_t)j * ND + lane];
}

// ---------------------------------------------------------------------------
// Kernel 4-FALLBACK: old per-(bh,u) flash attention (r6). Used only if
// ws_size is too small for the compact ctx buffer.
// ---------------------------------------------------------------------------
#define TJ 64
__global__ __launch_bounds__(256) void attn_rows_kernel(
        const float* __restrict__ Q,
        const float* __restrict__ K,
        const float* __restrict__ V,
        const int* __restrict__ Mtop,
        float* __restrict__ out) {
    int x = blockIdx.x;
    int xcd = x & 7;
    int slot = x >> 3;
    int grp = slot / NTOP;
    int u = slot % NTOP;
    int bh = grp * 8 + xcd;
    int h = bh & (NH - 1);
    int b = bh >> 3;
    int pos = Mtop[bh * NTOP + u];
    int n = pos + 1;
    int t = threadIdx.x;
    int r = t >> 2, qt = t & 3;

    __shared__ float Ks[TJ][65];
    __shared__ float Vs[TJ][65];
    __shared__ float red[256];

    const size_t rstride = (size_t)NH * ND;
    size_t base = (size_t)b * LSEQ * rstride + (size_t)h * ND;

    float qreg[16];
    const float* qrow = Q + base + (size_t)pos * rstride + qt * 16;
    #pragma unroll
    for (int i = 0; i < 16; i += 4) {
        float4 v4 = *reinterpret_cast<const float4*>(qrow + i);
        qreg[i] = v4.x; qreg[i + 1] = v4.y; qreg[i + 2] = v4.z; qreg[i + 3] = v4.w;
    }

    float m = -INFINITY, s = 0.0f;
    float o[16];
    #pragma unroll
    for (int dd = 0; dd < 16; ++dd) o[dd] = 0.0f;

    int ntiles = (n + TJ - 1) / TJ;
    for (int tt = 0; tt < ntiles; ++tt) {
        int j0 = tt * TJ;
        __syncthreads();
        #pragma unroll
        for (int i = 0; i < 4; ++i) {
            int u16 = t + i * 256;
            int rr = u16 >> 4, cc = u16 & 15;
            int j = j0 + rr;
            int jc = (j < n) ? j : (n - 1);
            const float* rowk = K + base + (size_t)jc * rstride;
            float4 kv = *reinterpret_cast<const float4*>(rowk + cc * 4);
            Ks[rr][cc * 4 + 0] = kv.x; Ks[rr][cc * 4 + 1] = kv.y;
            Ks[rr][cc * 4 + 2] = kv.z; Ks[rr][cc * 4 + 3] = kv.w;
            const float* rowv = V + base + (size_t)jc * rstride;
            float4 vv = *reinterpret_cast<const float4*>(rowv + cc * 4);
            Vs[rr][cc * 4 + 0] = vv.x; Vs[rr][cc * 4 + 1] = vv.y;
            Vs[rr][cc * 4 + 2] = vv.z; Vs[rr][cc * 4 + 3] = vv.w;
        }
        __syncthreads();

        int j = j0 + r;
        float acc = 0.0f;
        #pragma unroll
        for (int dd = 0; dd < 16; ++dd)
            acc = fmaf(qreg[dd], Ks[r][qt * 16 + dd], acc);
        acc += __shfl_xor(acc, 1, 64);
        acc += __shfl_xor(acc, 2, 64);

        if (j < n) {
            float sc = acc * 0.125f;
            if (sc > m) {
                float alpha = __expf(m - sc);
                s *= alpha;
                #pragma unroll
                for (int dd = 0; dd < 16; ++dd) o[dd] *= alpha;
                m = sc;
            }
            float e = __expf(sc - m);
            s += e;
            #pragma unroll
            for (int dd = 0; dd < 16; ++dd)
                o[dd] = fmaf(e, Vs[r][qt * 16 + dd], o[dd]);
        }
    }
    __syncthreads();

    red[t] = m; __syncthreads();
    for (int sft = 128; sft; sft >>= 1) {
        if (t < sft) red[t] = fmaxf(red[t], red[t + sft]);
        __syncthreads();
    }
    float mstar = red[0]; __syncthreads();
    float a = __expf(m - mstar);

    red[t] = s * a; __syncthreads();
    for (int sft = 128; sft; sft >>= 1) {
        if (t < sft) red[t] += red[t + sft];
        __syncthreads();
    }
    float S = red[0]; __syncthreads();

    float* OB = &Ks[0][0];
    #pragma unroll
    for (int dd = 0; dd < 16; ++dd) OB[t * 16 + dd] = o[dd] * a;
    __syncthreads();

    if (t < ND) {
        int qtt = t >> 4, dd = t & 15;
        float tot = 0.0f;
        for (int k = 0; k < 64; ++k) tot += OB[(4 * k + qtt) * 16 + dd];
        out[((size_t)bh * LSEQ + pos) * ND + t] = tot / S;
    }
}

// ---------------------------------------------------------------------------
extern "C" void kernel_launch(void* const* d_in, const int* in_sizes, int n_in,
                              void* d_out, int out_size, void* d_ws, size_t ws_size,
                              hipStream_t stream) {
    const float* Q = (const float*)d_in[0];
    const float* K = (const float*)d_in[1];
    const float* V = (const float*)d_in[2];
    const int* idxS = (const int*)d_in[3];
    float* out = (float*)d_out;

    // d_out scratch (all consumed before cumsum overwrites):
    //   M        @ 0     (512 KB)  -> topk
    //   sortedAB @ 1 MB  (768 KB)  -> compute_M
    //   part     @ 2 MB  (6.6 MB)  -> attn_merge
    // ws: Mtop (5760B) @0, chunkSums (128KB) @8192, ctx (360KB) @139264.
    float* Mbuf = (float*)d_out;
    int*   sortedAB = (int*)((char*)d_out + (1 << 20));
    float* part = (float*)((char*)d_out + (2 << 20));
    int*   Mtop = (int*)d_ws;
    float* chunkSums = (float*)((char*)d_ws + 8192);
    float* ctx = (float*)((char*)d_ws + 8192 + 131072);
    size_t wsNeeded = 8192 + 131072 + (size_t)NB * NH * NTOP * ND * 4;

    prep_kernel<<<LSEQ / 256, 256, 0, stream>>>(idxS, sortedAB);
    compute_M_kernel<<<512, 512, 0, stream>>>(Q, K, sortedAB, Mbuf);
    topk_kernel<<<NB * NH, 256, 0, stream>>>(Mbuf, Mtop);

    if (ws_size >= wsNeeded) {
        attn_partial_kernel<<<NB * NH * NCH, 256, 0, stream>>>(Q, K, V, Mtop, part);
        attn_merge_kernel<<<NB * NH * NTOP / 4, 256, 0, stream>>>(part, Mtop, ctx);
        cumsumA_kernel<<<NB * NH * 16, 256, 0, stream>>>(V, chunkSums);
        cumsumC_kernel<<<NB * NH * 16, 256, 0, stream>>>(V, chunkSums, out);
        scatter_kernel<<<NB * NH * NTOP / 4, 256, 0, stream>>>(ctx, Mtop, out);
    } else {
        cumsumA_kernel<<<NB * NH * 16, 256, 0, stream>>>(V, chunkSums);
        cumsumC_kernel<<<NB * NH * 16, 256, 0, stream>>>(V, chunkSums, out);
        attn_rows_kernel<<<NB * NH * NTOP, 256, 0, stream>>>(Q, K, V, Mtop, out);
    }
}